// Round 1
// baseline (452.346 us; speedup 1.0000x reference)
//
#include <hip/hip_runtime.h>
#include <hip/hip_bf16.h>

typedef __bf16 bf16;
typedef __bf16 bf16x8 __attribute__((ext_vector_type(8)));
typedef float  f32x4  __attribute__((ext_vector_type(4)));

#define MFMA16(a,b,c) __builtin_amdgcn_mfma_f32_16x16x32_bf16((a),(b),(c),0,0,0)

// ---------------------------------------------------------------------------
// sizes
// ---------------------------------------------------------------------------
static const int BATCH = 8;
static const int SEQ   = 2048;
static const int HID   = 512;       // in_features == hidden == 512
static const int MTOT  = BATCH * SEQ;  // 16384

// ---------------------------------------------------------------------------
// kernel 1: convert x (fp32) -> bf16, contiguous
// ---------------------------------------------------------------------------
__global__ void k_convert_x(const float* __restrict__ x, bf16* __restrict__ xb, int n4) {
    int i = blockIdx.x * blockDim.x + threadIdx.x;
    int stride = gridDim.x * blockDim.x;
    for (; i < n4; i += stride) {
        float4 v = ((const float4*)x)[i];
        union { bf16 h[4]; uint2 u; } o;
        o.h[0] = (bf16)v.x; o.h[1] = (bf16)v.y; o.h[2] = (bf16)v.z; o.h[3] = (bf16)v.w;
        ((uint2*)xb)[i] = o.u;
    }
}

// ---------------------------------------------------------------------------
// kernel 2: transpose W[512][512] fp32 -> WT[512][512] bf16  (z = q/k/v)
// ---------------------------------------------------------------------------
__global__ void k_transpose_w(const float* __restrict__ Wq, const float* __restrict__ Wk,
                              const float* __restrict__ Wv, bf16* __restrict__ wt) {
    int z = blockIdx.z;
    const float* W = (z == 0) ? Wq : (z == 1) ? Wk : Wv;
    bf16* WT = wt + (size_t)z * HID * HID;
    __shared__ float tile[32][33];
    int t  = threadIdx.x;
    int tx = t & 31, ty = t >> 5;             // 32 x 8
    int f0 = blockIdx.y * 32, h0 = blockIdx.x * 32;
    for (int i = 0; i < 32; i += 8)
        tile[ty + i][tx] = W[(size_t)(f0 + ty + i) * HID + h0 + tx];
    __syncthreads();
    for (int i = 0; i < 32; i += 8)
        WT[(size_t)(h0 + ty + i) * HID + f0 + tx] = (bf16)tile[tx][ty + i];
}

// ---------------------------------------------------------------------------
// kernel 3: QKV projection GEMM. C[z] = xb @ WT[z]^T + bias[z], z in {q,k,v}
// out is bf16 row-major [16384][512]; scale (1/sqrt(512)) folded into Q.
// 128x128 tile, BK=32, 4 waves each computing 64x64 (4x4 mfma tiles).
// ---------------------------------------------------------------------------
__global__ __launch_bounds__(256) void
k_qkv(const bf16* __restrict__ xb, const bf16* __restrict__ wt,
      const float* __restrict__ bq, const float* __restrict__ bk, const float* __restrict__ bv,
      bf16* __restrict__ qb, bf16* __restrict__ kb, bf16* __restrict__ vb) {
    int z = blockIdx.z;
    const bf16*  WT   = wt + (size_t)z * HID * HID;     // [n][k] layout
    const float* bias = (z == 0) ? bq : (z == 1) ? bk : bv;
    bf16*        out  = (z == 0) ? qb : (z == 1) ? kb : vb;
    float scale = (z == 0) ? 0.044194173824159216f : 1.0f;   // 1/sqrt(512)

    int m0 = blockIdx.y * 128, n0 = blockIdx.x * 128;
    __shared__ __align__(16) bf16 As[128][40];   // padded: row stride 80B -> conflict-free b128
    __shared__ __align__(16) bf16 Bs[128][40];

    int t = threadIdx.x;
    int w = t >> 6, lane = t & 63, quad = lane >> 4, l15 = lane & 15;
    int wr = w >> 1, wc = w & 1;

    f32x4 acc[4][4] = {};

    for (int k0 = 0; k0 < HID; k0 += 32) {
        __syncthreads();
        // stage A-tile [128][32] and B-tile [128][32]; 16B per thread per pass
        for (int i = 0; i < 2; i++) {
            int c = t + 256 * i;               // 0..511 chunk id
            int row = c >> 2, ch = c & 3;      // 4 chunks of 8 bf16 per row
            *(uint4*)&As[row][ch * 8] = *(const uint4*)&xb[(size_t)(m0 + row) * HID + k0 + ch * 8];
            *(uint4*)&Bs[row][ch * 8] = *(const uint4*)&WT[(size_t)(n0 + row) * HID + k0 + ch * 8];
        }
        __syncthreads();
        bf16x8 af[4], bf[4];
        for (int mt = 0; mt < 4; mt++) af[mt] = *(const bf16x8*)&As[wr * 64 + mt * 16 + l15][quad * 8];
        for (int nt = 0; nt < 4; nt++) bf[nt] = *(const bf16x8*)&Bs[wc * 64 + nt * 16 + l15][quad * 8];
        for (int mt = 0; mt < 4; mt++)
            for (int nt = 0; nt < 4; nt++)
                acc[mt][nt] = MFMA16(af[mt], bf[nt], acc[mt][nt]);
    }
    // epilogue: bias, scale, bf16 store
    for (int nt = 0; nt < 4; nt++) {
        int col = n0 + wc * 64 + nt * 16 + l15;
        float bc = bias[col];
        for (int mt = 0; mt < 4; mt++) {
            int rowb = m0 + wr * 64 + mt * 16 + quad * 4;
            for (int r = 0; r < 4; r++) {
                float v = (acc[mt][nt][r] + bc) * scale;
                out[(size_t)(rowb + r) * HID + col] = (bf16)v;
            }
        }
    }
}

// ---------------------------------------------------------------------------
// kernel 4: transpose V [b][s][h] -> VT [b][h][s]  (bf16)
// ---------------------------------------------------------------------------
__global__ void k_transpose_v(const bf16* __restrict__ vb, bf16* __restrict__ vt) {
    int b = blockIdx.z;
    int s0 = blockIdx.x * 64, h0 = blockIdx.y * 64;
    __shared__ bf16 tile[64][66];   // stride 132B = 33 dwords -> conflict-free columns
    int t = threadIdx.x;
    int tx = t & 63, ty = t >> 6;   // 64 x 4
    for (int i = 0; i < 64; i += 4)
        tile[ty + i][tx] = vb[((size_t)b * SEQ + s0 + ty + i) * HID + h0 + tx];
    __syncthreads();
    for (int i = 0; i < 64; i += 4)
        vt[((size_t)b * HID + h0 + ty + i) * SEQ + s0 + tx] = tile[tx][ty + i];
}

// ---------------------------------------------------------------------------
// kernel 5: flash attention. grid (batch=8, qblock=32), 256 threads (4 waves).
// Each wave owns 16 q rows; Q frags register-resident; keys swept in blocks
// of 32 through one shared buffer (K-tile then VT-tile); online softmax.
// ---------------------------------------------------------------------------
__global__ __launch_bounds__(256) void
k_attn(const bf16* __restrict__ qb, const bf16* __restrict__ kbuf,
       const bf16* __restrict__ vt, float* __restrict__ out) {
    int b = blockIdx.x, qblk = blockIdx.y;
    int t = threadIdx.x, w = t >> 6, lane = t & 63, quad = lane >> 4, l15 = lane & 15;

    // K-tile usage: [32][520] (pad 512->520 keeps 16B align, breaks bank aliasing)
    // VT-tile usage: [512][40] (pad 32->40)
    __shared__ __align__(16) bf16 sbuf[512 * 40];     // 40 KB, reused for both
    __shared__ __align__(16) bf16 pbuf[4][16][32];    // per-wave P round-trip, 4 KB

    const bf16* Qrow   = qb + ((size_t)b * SEQ + qblk * 64 + w * 16) * HID;
    const bf16* Kbase  = kbuf + (size_t)b * SEQ * HID;
    const bf16* VTbase = vt + (size_t)b * HID * SEQ;

    // Q fragments: A[m=l15][k=quad*8+j], 16 k-steps of 32
    bf16x8 qf[16];
    for (int kt = 0; kt < 16; kt++)
        qf[kt] = *(const bf16x8*)&Qrow[(size_t)l15 * HID + kt * 32 + quad * 8];

    float m_r[4], l_r[4];
    for (int r = 0; r < 4; r++) { m_r[r] = -1e30f; l_r[r] = 0.f; }
    f32x4 o_acc[32] = {};   // 16 rows x 512 cols per wave

    for (int kb0 = 0; kb0 < SEQ; kb0 += 32) {
        __syncthreads();   // previous iteration's PV reads of sbuf done
        // ---- stage K tile [32][512] -> sbuf stride 520
        for (int i = 0; i < 8; i++) {
            int c = t + 256 * i;            // 2048 chunks of 16B
            int row = c >> 6, ch = c & 63;
            *(uint4*)&sbuf[row * 520 + ch * 8] =
                *(const uint4*)&Kbase[(size_t)(kb0 + row) * HID + ch * 8];
        }
        __syncthreads();
        // ---- S = Q K^T  (16 q-rows x 32 keys per wave)
        f32x4 s[2] = {};
        for (int nt = 0; nt < 2; nt++)
            for (int kt = 0; kt < 16; kt++) {
                bf16x8 bf = *(const bf16x8*)&sbuf[(nt * 16 + l15) * 520 + kt * 32 + quad * 8];
                s[nt] = MFMA16(qf[kt], bf, s[nt]);
            }
        // ---- online softmax; row r of this wave = quad*4 + r
        float alpha[4];
        for (int r = 0; r < 4; r++) {
            float mx = fmaxf(s[0][r], s[1][r]);
            for (int d = 1; d < 16; d <<= 1) mx = fmaxf(mx, __shfl_xor(mx, d, 64));
            float mn = fmaxf(m_r[r], mx);
            alpha[r] = __expf(m_r[r] - mn);
            float p0 = __expf(s[0][r] - mn);
            float p1 = __expf(s[1][r] - mn);
            float rs = p0 + p1;
            for (int d = 1; d < 16; d <<= 1) rs += __shfl_xor(rs, d, 64);
            l_r[r] = l_r[r] * alpha[r] + rs;
            m_r[r] = mn;
            s[0][r] = p0; s[1][r] = p1;
        }
        for (int nt2 = 0; nt2 < 32; nt2++)
            for (int r = 0; r < 4; r++) o_acc[nt2][r] *= alpha[r];
        // ---- P (C-layout) -> LDS -> A-layout
        for (int nt = 0; nt < 2; nt++)
            for (int r = 0; r < 4; r++)
                pbuf[w][quad * 4 + r][nt * 16 + l15] = (bf16)s[nt][r];
        __syncthreads();   // all waves done reading K from sbuf
        // ---- stage VT tile [512][32] -> sbuf stride 40
        for (int i = 0; i < 8; i++) {
            int c = t + 256 * i;            // 2048 chunks of 16B
            int row = c >> 2, ch = c & 3;
            *(uint4*)&sbuf[row * 40 + ch * 8] =
                *(const uint4*)&VTbase[(size_t)row * SEQ + kb0 + ch * 8];
        }
        __syncthreads();
        // ---- O += P @ V   (one k-step of 32 keys; 32 h-tiles)
        bf16x8 pa = *(const bf16x8*)&pbuf[w][l15][quad * 8];
        for (int nt2 = 0; nt2 < 32; nt2++) {
            bf16x8 bv = *(const bf16x8*)&sbuf[(nt2 * 16 + l15) * 40 + quad * 8];
            o_acc[nt2] = MFMA16(pa, bv, o_acc[nt2]);
        }
    }
    // ---- epilogue: divide by l, store fp32
    float* orow = out + ((size_t)b * SEQ + qblk * 64 + w * 16) * HID;
    float inv_l[4];
    for (int r = 0; r < 4; r++) inv_l[r] = 1.0f / l_r[r];
    for (int nt2 = 0; nt2 < 32; nt2++) {
        int col = nt2 * 16 + l15;
        for (int r = 0; r < 4; r++)
            orow[(size_t)(quad * 4 + r) * HID + col] = o_acc[nt2][r] * inv_l[r];
    }
}

// ---------------------------------------------------------------------------
extern "C" void kernel_launch(void* const* d_in, const int* in_sizes, int n_in,
                              void* d_out, int out_size, void* d_ws, size_t ws_size,
                              hipStream_t stream) {
    const float* x  = (const float*)d_in[0];
    const float* Wq = (const float*)d_in[1];
    const float* bq = (const float*)d_in[2];
    const float* Wk = (const float*)d_in[3];
    const float* bk = (const float*)d_in[4];
    const float* Wv = (const float*)d_in[5];
    const float* bv = (const float*)d_in[6];
    float* out = (float*)d_out;

    char* ws = (char*)d_ws;
    const size_t SZ_XB = (size_t)MTOT * HID * 2;        // 16 MiB
    const size_t SZ_WT = (size_t)HID * HID * 2;         // 512 KiB each
    bf16* xb = (bf16*)(ws);
    bf16* wt = (bf16*)(ws + SZ_XB);
    bf16* qb = (bf16*)(ws + SZ_XB + 3 * SZ_WT);
    bf16* kb = (bf16*)(ws + SZ_XB + 3 * SZ_WT + SZ_XB);
    bf16* vb = (bf16*)(ws + SZ_XB + 3 * SZ_WT + 2 * SZ_XB);
    bf16* vtp = (bf16*)(ws + SZ_XB + 3 * SZ_WT + 3 * SZ_XB);

    k_convert_x<<<2048, 256, 0, stream>>>(x, xb, MTOT * HID / 4);
    k_transpose_w<<<dim3(16, 16, 3), 256, 0, stream>>>(Wq, Wk, Wv, wt);
    k_qkv<<<dim3(4, 128, 3), 256, 0, stream>>>(xb, wt, bq, bk, bv, qb, kb, vb);
    k_transpose_v<<<dim3(32, 8, 8), 256, 0, stream>>>(vb, vtp);
    k_attn<<<dim3(8, 32), 256, 0, stream>>>(qb, kb, vtp, out);
}

// Round 2
// 391.008 us; speedup vs baseline: 1.1569x; 1.1569x over previous
//
#include <hip/hip_runtime.h>
#include <hip/hip_bf16.h>

typedef __bf16 bf16;
typedef __bf16 bf16x8 __attribute__((ext_vector_type(8)));
typedef float  f32x4  __attribute__((ext_vector_type(4)));

#define MFMA16(a,b,c) __builtin_amdgcn_mfma_f32_16x16x32_bf16((a),(b),(c),0,0,0)

static const int BATCH = 8;
static const int SEQ   = 2048;
static const int HID   = 512;
static const int MTOT  = BATCH * SEQ;  // 16384

// async 16B global->LDS. LDS dest must be WAVE-UNIFORM; HW adds lane*16.
__device__ __forceinline__ void gl2lds16(const bf16* g, bf16* l) {
    __builtin_amdgcn_global_load_lds(
        (const __attribute__((address_space(1))) void*)g,
        (__attribute__((address_space(3))) void*)l, 16, 0, 0);
}

// ---------------------------------------------------------------------------
// kernel 1: convert x (fp32) -> bf16
// ---------------------------------------------------------------------------
__global__ void k_convert_x(const float* __restrict__ x, bf16* __restrict__ xb, int n4) {
    int i = blockIdx.x * blockDim.x + threadIdx.x;
    int stride = gridDim.x * blockDim.x;
    for (; i < n4; i += stride) {
        float4 v = ((const float4*)x)[i];
        union { bf16 h[4]; uint2 u; } o;
        o.h[0] = (bf16)v.x; o.h[1] = (bf16)v.y; o.h[2] = (bf16)v.z; o.h[3] = (bf16)v.w;
        ((uint2*)xb)[i] = o.u;
    }
}

// ---------------------------------------------------------------------------
// kernel 2: transpose W[512][512] fp32 -> WT[512][512] bf16  (z = q/k/v)
// ---------------------------------------------------------------------------
__global__ void k_transpose_w(const float* __restrict__ Wq, const float* __restrict__ Wk,
                              const float* __restrict__ Wv, bf16* __restrict__ wt) {
    int z = blockIdx.z;
    const float* W = (z == 0) ? Wq : (z == 1) ? Wk : Wv;
    bf16* WT = wt + (size_t)z * HID * HID;
    __shared__ float tile[32][33];
    int t  = threadIdx.x;
    int tx = t & 31, ty = t >> 5;
    int f0 = blockIdx.y * 32, h0 = blockIdx.x * 32;
    for (int i = 0; i < 32; i += 8)
        tile[ty + i][tx] = W[(size_t)(f0 + ty + i) * HID + h0 + tx];
    __syncthreads();
    for (int i = 0; i < 32; i += 8)
        WT[(size_t)(h0 + ty + i) * HID + f0 + tx] = (bf16)tile[tx][ty + i];
}

// ---------------------------------------------------------------------------
// kernel 3: QKV projection GEMM (unchanged from R1 — ~30us, not the bottleneck)
// ---------------------------------------------------------------------------
__global__ __launch_bounds__(256) void
k_qkv(const bf16* __restrict__ xb, const bf16* __restrict__ wt,
      const float* __restrict__ bq, const float* __restrict__ bk, const float* __restrict__ bv,
      bf16* __restrict__ qb, bf16* __restrict__ kb, bf16* __restrict__ vb) {
    int z = blockIdx.z;
    const bf16*  WT   = wt + (size_t)z * HID * HID;
    const float* bias = (z == 0) ? bq : (z == 1) ? bk : bv;
    bf16*        out  = (z == 0) ? qb : (z == 1) ? kb : vb;
    float scale = (z == 0) ? 0.044194173824159216f : 1.0f;   // 1/sqrt(512) folded into Q

    int m0 = blockIdx.y * 128, n0 = blockIdx.x * 128;
    __shared__ __align__(16) bf16 As[128][40];
    __shared__ __align__(16) bf16 Bs[128][40];

    int t = threadIdx.x;
    int w = t >> 6, lane = t & 63, quad = lane >> 4, l15 = lane & 15;
    int wr = w >> 1, wc = w & 1;

    f32x4 acc[4][4] = {};

    for (int k0 = 0; k0 < HID; k0 += 32) {
        __syncthreads();
        for (int i = 0; i < 2; i++) {
            int c = t + 256 * i;
            int row = c >> 2, ch = c & 3;
            *(uint4*)&As[row][ch * 8] = *(const uint4*)&xb[(size_t)(m0 + row) * HID + k0 + ch * 8];
            *(uint4*)&Bs[row][ch * 8] = *(const uint4*)&WT[(size_t)(n0 + row) * HID + k0 + ch * 8];
        }
        __syncthreads();
        bf16x8 af[4], bfr[4];
        for (int mt = 0; mt < 4; mt++) af[mt] = *(const bf16x8*)&As[wr * 64 + mt * 16 + l15][quad * 8];
        for (int nt = 0; nt < 4; nt++) bfr[nt] = *(const bf16x8*)&Bs[wc * 64 + nt * 16 + l15][quad * 8];
        for (int mt = 0; mt < 4; mt++)
            for (int nt = 0; nt < 4; nt++)
                acc[mt][nt] = MFMA16(af[mt], bfr[nt], acc[mt][nt]);
    }
    for (int nt = 0; nt < 4; nt++) {
        int col = n0 + wc * 64 + nt * 16 + l15;
        float bc = bias[col];
        for (int mt = 0; mt < 4; mt++) {
            int rowb = m0 + wr * 64 + mt * 16 + quad * 4;
            for (int r = 0; r < 4; r++) {
                float v = (acc[mt][nt][r] + bc) * scale;
                out[(size_t)(rowb + r) * HID + col] = (bf16)v;
            }
        }
    }
}

// ---------------------------------------------------------------------------
// kernel 4: transpose V [b][s][h] -> VT [b][h][s]  (bf16)
// ---------------------------------------------------------------------------
__global__ void k_transpose_v(const bf16* __restrict__ vb, bf16* __restrict__ vt) {
    int b = blockIdx.z;
    int s0 = blockIdx.x * 64, h0 = blockIdx.y * 64;
    __shared__ bf16 tile[64][66];
    int t = threadIdx.x;
    int tx = t & 63, ty = t >> 6;
    for (int i = 0; i < 64; i += 4)
        tile[ty + i][tx] = vb[((size_t)b * SEQ + s0 + ty + i) * HID + h0 + tx];
    __syncthreads();
    for (int i = 0; i < 64; i += 4)
        vt[((size_t)b * HID + h0 + ty + i) * SEQ + s0 + tx] = tile[tx][ty + i];
}

// ---------------------------------------------------------------------------
// kernel 5: flash attention, async-pipelined.
// 256 blocks (1D; batch = j&7 so one batch's blocks share an XCD), 4 waves,
// 16 q-rows/wave. Double-buffered K/V tiles (32 keys) filled by
// global_load_lds DMA issued one iteration ahead; ONE barrier per iteration.
// K tile XOR-swizzled (chunk' = chunk ^ (row&7)): DMA needs lane-contiguous
// LDS, swizzle replaces padding for conflict-free b128 reads.
// ---------------------------------------------------------------------------
__global__ __launch_bounds__(256) void
k_attn(const bf16* __restrict__ qb, const bf16* __restrict__ kbuf,
       const bf16* __restrict__ vt, float* __restrict__ out) {
    int j = blockIdx.x;
    int b = j & 7, qblk = j >> 3;
    int t = threadIdx.x, w = t >> 6, lane = t & 63, quad = lane >> 4, l15 = lane & 15;

    // K: [2][32 keys][64 chunks of 16B] swizzled; V: [2][512 h][4 chunks] linear
    __shared__ __align__(16) bf16 kls[2][32 * 512];   // 64 KB
    __shared__ __align__(16) bf16 vls[2][512 * 32];   // 64 KB
    __shared__ __align__(16) bf16 pb[4][16][36];      // per-wave P round-trip

    const bf16* Qrow   = qb + ((size_t)b * SEQ + qblk * 64 + w * 16) * HID;
    const bf16* Kbase  = kbuf + (size_t)b * SEQ * HID;
    const bf16* VTbase = vt + (size_t)b * HID * SEQ;

    // Q fragments, register-resident: A[m=l15][k=quad*8+j], 16 k-steps
    bf16x8 qf[16];
    for (int kt = 0; kt < 16; kt++)
        qf[kt] = *(const bf16x8*)&Qrow[(size_t)l15 * HID + kt * 32 + quad * 8];

    float m_r[4], l_r[4];
    for (int r = 0; r < 4; r++) { m_r[r] = -1e30f; l_r[r] = 0.f; }
    f32x4 o_acc[32] = {};

    const int NIT = SEQ / 32;   // 64

    // ---- stage a tile (iteration index it) into buffer slot s
    auto stage = [&](int it, int s) {
        int kb0 = it * 32;
        // K tile: 2048 chunks; wave w, issue jj: chunks jj*256 + w*64 + lane
        for (int jj = 0; jj < 8; jj++) {
            int p = jj * 256 + w * 64 + lane;
            int r = p >> 6, cc = p & 63;
            const bf16* g = Kbase + (size_t)(kb0 + r) * HID + ((cc ^ (r & 7)) * 8);
            gl2lds16(g, &kls[s][(size_t)(jj * 256 + w * 64) * 8]);
        }
        // V tile: rows h (512), 4 chunks of 16B each (32 keys)
        for (int jj = 0; jj < 8; jj++) {
            int p = jj * 256 + w * 64 + lane;
            int r = p >> 2, cc = p & 3;
            const bf16* g = VTbase + (size_t)r * SEQ + kb0 + cc * 8;
            gl2lds16(g, &vls[s][(size_t)(jj * 256 + w * 64) * 8]);
        }
    };

    stage(0, 0);
    __syncthreads();   // compiler drains vmcnt(0) before s_barrier

    for (int i = 0; i < NIT; i++) {
        int cur = i & 1, nxt = cur ^ 1;
        int ii = (i + 1 < NIT) ? i + 1 : NIT - 1;
        stage(ii, nxt);          // async DMA for next tile, in flight all iter

        const bf16* kcur = kls[cur];
        const bf16* vcur = vls[cur];

        // ---- S = Q K^T  (16 q-rows x 32 keys per wave)
        f32x4 s[2] = {};
        for (int nt = 0; nt < 2; nt++)
            for (int kt = 0; kt < 16; kt++) {
                int pos = ((nt * 16 + l15) << 6) | ((kt * 4 + quad) ^ (l15 & 7));
                bf16x8 kf = *(const bf16x8*)&kcur[pos * 8];
                s[nt] = MFMA16(qf[kt], kf, s[nt]);
            }

        // ---- online softmax (rows quad*4+r of this wave's 16)
        float alpha[4];
        for (int r = 0; r < 4; r++) {
            float mx = fmaxf(s[0][r], s[1][r]);
            for (int d = 1; d < 16; d <<= 1) mx = fmaxf(mx, __shfl_xor(mx, d, 64));
            float mn = fmaxf(m_r[r], mx);
            alpha[r] = __expf(m_r[r] - mn);
            float p0 = __expf(s[0][r] - mn);
            float p1 = __expf(s[1][r] - mn);
            float rs = p0 + p1;
            for (int d = 1; d < 16; d <<= 1) rs += __shfl_xor(rs, d, 64);
            l_r[r] = l_r[r] * alpha[r] + rs;
            m_r[r] = mn;
            s[0][r] = p0; s[1][r] = p1;
        }
        for (int nt2 = 0; nt2 < 32; nt2++)
            for (int r = 0; r < 4; r++) o_acc[nt2][r] *= alpha[r];

        // ---- P (C-layout) -> per-wave LDS -> A-layout (no barrier needed)
        for (int nt = 0; nt < 2; nt++)
            for (int r = 0; r < 4; r++)
                pb[w][quad * 4 + r][nt * 16 + l15] = (bf16)s[nt][r];
        bf16x8 pa = *(const bf16x8*)&pb[w][l15][quad * 8];

        // ---- O += P @ V
        for (int nt2 = 0; nt2 < 32; nt2++) {
            int pos = ((nt2 * 16 + l15) << 2) | quad;
            bf16x8 vf = *(const bf16x8*)&vcur[pos * 8];
            o_acc[nt2] = MFMA16(pa, vf, o_acc[nt2]);
        }

        __syncthreads();   // drains our DMA (vmcnt 0) + retires reads of cur
    }

    // ---- epilogue
    float* orow = out + ((size_t)b * SEQ + qblk * 64 + w * 16) * HID;
    float inv_l[4];
    for (int r = 0; r < 4; r++) inv_l[r] = 1.0f / l_r[r];
    for (int nt2 = 0; nt2 < 32; nt2++) {
        int col = nt2 * 16 + l15;
        for (int r = 0; r < 4; r++)
            orow[(size_t)(quad * 4 + r) * HID + col] = o_acc[nt2][r] * inv_l[r];
    }
}

// ---------------------------------------------------------------------------
extern "C" void kernel_launch(void* const* d_in, const int* in_sizes, int n_in,
                              void* d_out, int out_size, void* d_ws, size_t ws_size,
                              hipStream_t stream) {
    const float* x  = (const float*)d_in[0];
    const float* Wq = (const float*)d_in[1];
    const float* bq = (const float*)d_in[2];
    const float* Wk = (const float*)d_in[3];
    const float* bk = (const float*)d_in[4];
    const float* Wv = (const float*)d_in[5];
    const float* bv = (const float*)d_in[6];
    float* out = (float*)d_out;

    char* ws = (char*)d_ws;
    const size_t SZ_XB = (size_t)MTOT * HID * 2;        // 16 MiB
    const size_t SZ_WT = (size_t)HID * HID * 2;         // 512 KiB each
    bf16* xb  = (bf16*)(ws);
    bf16* wt  = (bf16*)(ws + SZ_XB);
    bf16* qb  = (bf16*)(ws + SZ_XB + 3 * SZ_WT);
    bf16* kb  = (bf16*)(ws + SZ_XB + 3 * SZ_WT + SZ_XB);
    bf16* vb  = (bf16*)(ws + SZ_XB + 3 * SZ_WT + 2 * SZ_XB);
    bf16* vtp = (bf16*)(ws + SZ_XB + 3 * SZ_WT + 3 * SZ_XB);

    k_convert_x<<<2048, 256, 0, stream>>>(x, xb, MTOT * HID / 4);
    k_transpose_w<<<dim3(16, 16, 3), 256, 0, stream>>>(Wq, Wk, Wv, wt);
    k_qkv<<<dim3(4, 128, 3), 256, 0, stream>>>(xb, wt, bq, bk, bv, qb, kb, vb);
    k_transpose_v<<<dim3(32, 8, 8), 256, 0, stream>>>(vb, vtp);
    k_attn<<<256, 256, 0, stream>>>(qb, kb, vtp, out);
}